// Round 3
// baseline (284.395 us; speedup 1.0000x reference)
//
#include <hip/hip_runtime.h>
#include <hip/hip_bf16.h>
#include <cmath>

// ---------- reduction helpers (wave64) ----------
__device__ inline float waveReduceSum(float v) {
#pragma unroll
    for (int o = 32; o > 0; o >>= 1) v += __shfl_xor(v, o, 64);
    return v;
}
__device__ inline float waveReduceMax(float v) {
#pragma unroll
    for (int o = 32; o > 0; o >>= 1) v = fmaxf(v, __shfl_xor(v, o, 64));
    return v;
}
// valid result on thread 0 only; block size 256 (4 waves)
__device__ inline float blockReduceSum(float v, float* s) {
    int lane = threadIdx.x & 63, wv = threadIdx.x >> 6;
    v = waveReduceSum(v);
    if (lane == 0) s[wv] = v;
    __syncthreads();
    float r = 0.f;
    if (wv == 0) {
        r = (lane < 4) ? s[lane] : 0.f;
        r = waveReduceSum(r);
    }
    __syncthreads();
    return r;
}

#define H 256
#define W 256
#define NIMG 64
#define HW 65536
#define RG 8    // rows per block in k_pairwise

// ---------- kernel A: pairwise loss partials (sigmoid-space, barrier-free loop) ----------
// sim = -log( sig_c*sig_n + (1-sig_c)*(1-sig_n) ); padded neighbor -> P=1 -> sim=0.
__global__ __launch_bounds__(256) void k_pairwise(
    const float* __restrict__ src, const float* __restrict__ ts,
    const int* __restrict__ bm,
    float* __restrict__ part_st, float* __restrict__ part_t)
{
    __shared__ float s_sig[RG + 4][W];
    __shared__ float red[4];
    const int hg = blockIdx.x, n = blockIdx.y, w = threadIdx.x;
    const int h0 = hg * RG;
    const float* srcn = src + (size_t)n * HW;
    // stage RG+4 rows of sigmoid(x)
#pragma unroll
    for (int r = 0; r < RG + 4; r++) {
        const int gr = h0 - 2 + r;
        float s = 0.5f;
        if (gr >= 0 && gr < H) {
            const float x = srcn[gr * W + w];
            s = __builtin_amdgcn_rcpf(1.f + __expf(-x));
        }
        s_sig[r][w] = s;
    }
    __syncthreads();
    const int* bmn = bm + (size_t)n * HW;
    const float* tsbase = ts + (size_t)n * 8 * HW + w;

    const int DR[8] = {-2, -2, -2, 0, 0, 2, 2, 2};
    const int DC[8] = {-2, 0, 2, -2, 2, -2, 0, 2};
    float st = 0.f, tt = 0.f;
#pragma unroll
    for (int rr = 0; rr < RG; rr++) {
        const int h = h0 + rr;
        const int ci = rr + 2;
        const float sc = s_sig[ci][w];
        const float omc = 1.f - sc;
        const float bmf = (float)bmn[h * W + w];
        const float* tsn = tsbase + h * W;
#pragma unroll
        for (int p = 0; p < 8; p++) {
            const int hr = h + DR[p];
            const int wc = w + DC[p];
            const bool valid = (hr >= 0) && (hr < H) && (wc >= 0) && (wc < W);
            const int wcc = min(max(wc, 0), W - 1);
            const float sn = s_sig[ci + DR[p]][wcc];
            const float P = valid ? fmaf(sc, sn, omc * (1.f - sn)) : 1.f;
            const float tsv = tsn[(size_t)p * HW];
            const float tg = (tsv >= 0.3f) ? bmf : 0.f;
            st = fmaf(-__logf(P), tg, st);
            tt += tg;
        }
    }
    const float sst = blockReduceSum(st, red);
    const float stt = blockReduceSum(tt, red);
    if (threadIdx.x == 0) {
        const int o = n * 32 + hg;
        part_st[o] = sst;
        part_t[o] = stt;
    }
}

// ---------- kernel B: column-max partials + row maxes in one pass ----------
__global__ __launch_bounds__(256) void k_maxes(
    const float* __restrict__ src, const int* __restrict__ bm,
    float* __restrict__ colpart_x, float* __restrict__ colpart_b,
    float* __restrict__ rowmax_x, float* __restrict__ rowmax_b)
{
    __shared__ float sx[32][4];
    __shared__ float sb[32][4];
    const int chunk = blockIdx.x, n = blockIdx.y, t = threadIdx.x;
    const int lane = t & 63, wv = t >> 6;
    const float* s = src + (size_t)n * HW + chunk * 32 * W + t;
    const int* b = bm + (size_t)n * HW + chunk * 32 * W + t;
    float cmx = -3.4e38f, cmb = 0.f;
#pragma unroll 4
    for (int r = 0; r < 32; r++) {
        const float x = s[r * W];
        const float bf = (float)b[r * W];
        cmx = fmaxf(cmx, x);
        cmb = fmaxf(cmb, bf);
        const float rx = waveReduceMax(x);
        const float rb = waveReduceMax(bf);
        if (lane == 0) { sx[r][wv] = rx; sb[r][wv] = rb; }
    }
    const int o = (n * 8 + chunk) * W + t;
    colpart_x[o] = cmx;
    colpart_b[o] = cmb;
    __syncthreads();
    if (t < 32) {
        const float m = fmaxf(fmaxf(sx[t][0], sx[t][1]), fmaxf(sx[t][2], sx[t][3]));
        rowmax_x[n * H + chunk * 32 + t] = m;
    } else if (t < 64) {
        const int r = t - 32;
        const float m = fmaxf(fmaxf(sb[r][0], sb[r][1]), fmaxf(sb[r][2], sb[r][3]));
        rowmax_b[n * H + chunk * 32 + r] = m;
    }
}

// ---------- kernel C: per-image projection loss ----------
__global__ __launch_bounds__(256) void k_proj(
    const float* __restrict__ colpart_x, const float* __restrict__ colpart_b,
    const float* __restrict__ rowmax_x, const float* __restrict__ rowmax_b,
    float* __restrict__ proj)
{
    __shared__ float red[4];
    const int n = blockIdx.x, t = threadIdx.x;
    float cx = -3.4e38f, cb = 0.f;
#pragma unroll
    for (int c = 0; c < 8; c++) {
        cx = fmaxf(cx, colpart_x[(n * 8 + c) * W + t]);
        cb = fmaxf(cb, colpart_b[(n * 8 + c) * W + t]);
    }
    const float iy = 1.f / (1.f + expf(-cx));
    const float ty = cb;
    const float ix = 1.f / (1.f + expf(-rowmax_x[n * H + t]));
    const float tx = rowmax_b[n * H + t];

    const float Sxy = blockReduceSum(ix * tx, red);
    const float Sxx = blockReduceSum(ix * ix, red);
    const float Stx = blockReduceSum(tx * tx, red);
    const float Syw = blockReduceSum(iy * ty, red);
    const float Syy = blockReduceSum(iy * iy, red);
    const float Sty = blockReduceSum(ty * ty, red);
    if (t == 0) {
        const float eps = 0.001f;
        const float lx = 1.f - 2.f * Sxy / (Sxx + Stx + eps);
        const float ly = 1.f - 2.f * Syw / (Syy + Sty + eps);
        proj[n] = lx + ly;
    }
}

// ---------- kernel D: CE + final combine ----------
__global__ __launch_bounds__(256) void k_final(
    const float* __restrict__ logits, const int* __restrict__ tcls,
    const float* __restrict__ ew, const int* __restrict__ num_masks,
    const float* __restrict__ part_st, const float* __restrict__ part_t,
    const float* __restrict__ proj, float* __restrict__ out)
{
    __shared__ float red[4];
    const int t = threadIdx.x;
    float s1 = 0.f, s2 = 0.f;
    for (int i = t; i < NIMG * 32; i += 256) { s1 += part_st[i]; s2 += part_t[i]; }
    const float sum_st = blockReduceSum(s1, red);
    const float sum_t = blockReduceSum(s2, red);
    const float pj = (t < NIMG) ? proj[t] : 0.f;
    const float sum_pj = blockReduceSum(pj, red);

    float wn = 0.f, wsum = 0.f;
    if (t < 200) {
        const float* row = logits + t * 81;
        float mx = -3.4e38f;
        for (int c = 0; c < 81; c++) mx = fmaxf(mx, row[c]);
        float se = 0.f;
        for (int c = 0; c < 81; c++) se += expf(row[c] - mx);
        const float lse = mx + logf(se);
        const int tc = tcls[t];
        const float nll = lse - row[tc];
        const float wv = ew[tc];
        wn = wv * nll;
        wsum = wv;
    }
    const float Swn = blockReduceSum(wn, red);
    const float Sw = blockReduceSum(wsum, red);
    if (t == 0) {
        const float nm = (float)max(num_masks[0], 1);
        const float loss_ce = Swn / Sw;
        const float loss_pw = sum_st / fmaxf(sum_t, 1.f) / nm;
        const float loss_pj = sum_pj / nm;
        out[0] = loss_ce + loss_pw + loss_pj;
    }
}

extern "C" void kernel_launch(void* const* d_in, const int* in_sizes, int n_in,
                              void* d_out, int out_size, void* d_ws, size_t ws_size,
                              hipStream_t stream) {
    const float* pred_logits = (const float*)d_in[0];  // [2,100,81]
    const float* src         = (const float*)d_in[1];  // [64,256,256]
    const float* ew          = (const float*)d_in[2];  // [81]
    const float* ts          = (const float*)d_in[3];  // [64,8,256,256]
    const int*   tcls        = (const int*)d_in[4];    // [2,100]
    const int*   bm          = (const int*)d_in[5];    // [64,256,256]
    const int*   nmasks      = (const int*)d_in[6];    // [1]
    float* out = (float*)d_out;

    float* ws = (float*)d_ws;
    float* part_st   = ws;            // 2048
    float* part_t    = ws + 2048;     // 2048
    float* rowmax_x  = ws + 4096;     // 16384
    float* rowmax_b  = ws + 20480;    // 16384
    float* colpart_x = ws + 36864;    // 64*8*256 = 131072
    float* colpart_b = ws + 167936;   // 131072
    float* proj      = ws + 299008;   // 64

    k_pairwise<<<dim3(32, NIMG), 256, 0, stream>>>(src, ts, bm, part_st, part_t);
    k_maxes<<<dim3(8, NIMG), 256, 0, stream>>>(src, bm, colpart_x, colpart_b, rowmax_x, rowmax_b);
    k_proj<<<NIMG, 256, 0, stream>>>(colpart_x, colpart_b, rowmax_x, rowmax_b, proj);
    k_final<<<1, 256, 0, stream>>>(pred_logits, tcls, ew, nmasks, part_st, part_t, proj, out);
}

// Round 4
// 258.242 us; speedup vs baseline: 1.1013x; 1.1013x over previous
//
#include <hip/hip_runtime.h>
#include <hip/hip_bf16.h>
#include <cmath>

#define H 256
#define W 256
#define NIMG 64
#define HW 65536
#define RG 8       // rows per block
#define NROWG 32   // H / RG

// ---------- reduction helpers (wave64) ----------
__device__ inline float waveReduceSum(float v) {
#pragma unroll
    for (int o = 32; o > 0; o >>= 1) v += __shfl_xor(v, o, 64);
    return v;
}
__device__ inline float waveReduceMax(float v) {
#pragma unroll
    for (int o = 32; o > 0; o >>= 1) v = fmaxf(v, __shfl_xor(v, o, 64));
    return v;
}
// valid result on thread 0 only; block size 256 (4 waves)
__device__ inline float blockReduceSum(float v, float* s) {
    int lane = threadIdx.x & 63, wv = threadIdx.x >> 6;
    v = waveReduceSum(v);
    if (lane == 0) s[wv] = v;
    __syncthreads();
    float r = 0.f;
    if (wv == 0) {
        r = (lane < 4) ? s[lane] : 0.f;
        r = waveReduceSum(r);
    }
    __syncthreads();
    return r;
}

// ---------- kernel A: pairwise partials + ALL row/col maxes, float4 loads ----------
// sim = -log( sig_c*sig_n + (1-sig_c)*(1-sig_n) ); padded neighbor -> P=1 -> sim=0.
__global__ __launch_bounds__(256) void k_pairwise(
    const float* __restrict__ src, const float* __restrict__ ts,
    const int* __restrict__ bm,
    float* __restrict__ part_st, float* __restrict__ part_t,
    float* __restrict__ rowsig, float* __restrict__ rowmax_b,
    float* __restrict__ colpart_s, float* __restrict__ colpart_b)
{
    __shared__ float s_sig[12][264];   // 4-float pad on each side
    __shared__ float red[4];
    const int hg = blockIdx.x, n = blockIdx.y, t = threadIdx.x;
    const int h0 = hg * RG;
    const int lane = t & 63, wv = t >> 6;
    const float* srcn = src + (size_t)n * HW;

    // init pads (rows 12 x 8 pad floats); value irrelevant (select discards), keep finite
    if (t < 96) {
        const int row = t >> 3, j = t & 7;
        const int idx = (j < 4) ? j : (256 + j);   // 0..3 and 260..263
        s_sig[row][idx] = 0.5f;
    }
    // stage 12 rows of sigmoid(x), float4 per thread x3
#pragma unroll
    for (int k = 0; k < 3; k++) {
        const int idx = t + k * 256;           // 768 float4 slots
        const int row = idx >> 6;
        const int col = (idx & 63) << 2;
        const int gr = h0 - 2 + row;
        float4 xv = make_float4(0.f, 0.f, 0.f, 0.f);
        if (gr >= 0 && gr < H) xv = *reinterpret_cast<const float4*>(srcn + gr * W + col);
        float4 sv;
        sv.x = __builtin_amdgcn_rcpf(1.f + __expf(-xv.x));
        sv.y = __builtin_amdgcn_rcpf(1.f + __expf(-xv.y));
        sv.z = __builtin_amdgcn_rcpf(1.f + __expf(-xv.z));
        sv.w = __builtin_amdgcn_rcpf(1.f + __expf(-xv.w));
        *reinterpret_cast<float4*>(&s_sig[row][4 + col]) = sv;
    }
    __syncthreads();

    const int* bmn = bm + (size_t)n * HW;
    const float* tsn = ts + (size_t)n * 8 * HW;
    const int c0 = lane << 2;              // global col of pixel 0 (wave covers full row)

    float st = 0.f, tt = 0.f;
    float cms[4] = {0.f, 0.f, 0.f, 0.f};
    float cmb[4] = {0.f, 0.f, 0.f, 0.f};

    // wave wv handles rows {wv, wv+4}
    for (int rr = wv; rr < RG; rr += 4) {
        const int h = h0 + rr;
        const int ci = rr + 2;
        const bool rvt = (h - 2) >= 0;
        const bool rvb = (h + 2) < H;

        const int4 bi = *reinterpret_cast<const int4*>(bmn + h * W + c0);
        float4 tv[8];
#pragma unroll
        for (int p = 0; p < 8; p++)
            tv[p] = *reinterpret_cast<const float4*>(tsn + (size_t)p * HW + h * W + c0);

        float ftop[12], fmid[12], fbot[12];
        *reinterpret_cast<float4*>(&ftop[0]) = *reinterpret_cast<const float4*>(&s_sig[ci - 2][c0]);
        *reinterpret_cast<float4*>(&ftop[4]) = *reinterpret_cast<const float4*>(&s_sig[ci - 2][c0 + 4]);
        *reinterpret_cast<float4*>(&ftop[8]) = *reinterpret_cast<const float4*>(&s_sig[ci - 2][c0 + 8]);
        *reinterpret_cast<float4*>(&fmid[0]) = *reinterpret_cast<const float4*>(&s_sig[ci][c0]);
        *reinterpret_cast<float4*>(&fmid[4]) = *reinterpret_cast<const float4*>(&s_sig[ci][c0 + 4]);
        *reinterpret_cast<float4*>(&fmid[8]) = *reinterpret_cast<const float4*>(&s_sig[ci][c0 + 8]);
        *reinterpret_cast<float4*>(&fbot[0]) = *reinterpret_cast<const float4*>(&s_sig[ci + 2][c0]);
        *reinterpret_cast<float4*>(&fbot[4]) = *reinterpret_cast<const float4*>(&s_sig[ci + 2][c0 + 4]);
        *reinterpret_cast<float4*>(&fbot[8]) = *reinterpret_cast<const float4*>(&s_sig[ci + 2][c0 + 8]);

        const float* tvp = reinterpret_cast<const float*>(tv);
        float msc = 0.f, mb = 0.f;
#pragma unroll
        for (int p = 0; p < 4; p++) {
            const float sc = fmid[4 + p];      // f[i] = col c0-4+i; center at 4+p
            const float omc = 1.f - sc;
            const float bmf = (float)reinterpret_cast<const int*>(&bi)[p];
            const bool cl = (c0 + p - 2) >= 0;
            const bool cr = (c0 + p + 2) < W;
            msc = fmaxf(msc, sc); mb = fmaxf(mb, bmf);
            cms[p] = fmaxf(cms[p], sc); cmb[p] = fmaxf(cmb[p], bmf);

            auto tap = [&](float sn, bool valid, float tsv) {
                const float tg = (tsv >= 0.3f) ? bmf : 0.f;
                tt += tg;
                const float P = valid ? fmaf(sc, sn, omc * (1.f - sn)) : 1.f;
                st = fmaf(-__logf(P), tg, st);
            };
            // tap order matches unfold (i-major, j-minor, center removed)
            tap(ftop[2 + p], rvt && cl, tvp[0 * 4 + p]);
            tap(ftop[4 + p], rvt,       tvp[1 * 4 + p]);
            tap(ftop[6 + p], rvt && cr, tvp[2 * 4 + p]);
            tap(fmid[2 + p], cl,        tvp[3 * 4 + p]);
            tap(fmid[6 + p], cr,        tvp[4 * 4 + p]);
            tap(fbot[2 + p], rvb && cl, tvp[5 * 4 + p]);
            tap(fbot[4 + p], rvb,       tvp[6 * 4 + p]);
            tap(fbot[6 + p], rvb && cr, tvp[7 * 4 + p]);
        }
        // per-row maxes: wave owns the whole row -> pure wave reduce, no barrier
        const float wms = waveReduceMax(msc);
        const float wmb = waveReduceMax(mb);
        if (lane == 0) {
            rowsig[n * H + h] = wms;      // sigmoid-space (monotone)
            rowmax_b[n * H + h] = wmb;
        }
    }
    // column partial maxes for this row-group
    const int co = (n * NROWG + hg) * W + c0;
    *reinterpret_cast<float4*>(&colpart_s[co]) = make_float4(cms[0], cms[1], cms[2], cms[3]);
    *reinterpret_cast<float4*>(&colpart_b[co]) = make_float4(cmb[0], cmb[1], cmb[2], cmb[3]);

    const float sst = blockReduceSum(st, red);
    const float stt = blockReduceSum(tt, red);
    if (t == 0) {
        const int o = n * NROWG + hg;
        part_st[o] = sst;
        part_t[o] = stt;
    }
}

// ---------- kernel B: per-image projection loss ----------
__global__ __launch_bounds__(256) void k_proj(
    const float* __restrict__ colpart_s, const float* __restrict__ colpart_b,
    const float* __restrict__ rowsig, const float* __restrict__ rowmax_b,
    float* __restrict__ proj)
{
    __shared__ float red[4];
    const int n = blockIdx.x, t = threadIdx.x;
    float cs = 0.f, cb = 0.f;
#pragma unroll 8
    for (int c = 0; c < NROWG; c++) {
        cs = fmaxf(cs, colpart_s[(n * NROWG + c) * W + t]);
        cb = fmaxf(cb, colpart_b[(n * NROWG + c) * W + t]);
    }
    const float iy = cs;                   // already sigmoid(max x)
    const float ty = cb;
    const float ix = rowsig[n * H + t];
    const float tx = rowmax_b[n * H + t];

    const float Sxy = blockReduceSum(ix * tx, red);
    const float Sxx = blockReduceSum(ix * ix, red);
    const float Stx = blockReduceSum(tx * tx, red);
    const float Syw = blockReduceSum(iy * ty, red);
    const float Syy = blockReduceSum(iy * iy, red);
    const float Sty = blockReduceSum(ty * ty, red);
    if (t == 0) {
        const float eps = 0.001f;
        const float lx = 1.f - 2.f * Sxy / (Sxx + Stx + eps);
        const float ly = 1.f - 2.f * Syw / (Syy + Sty + eps);
        proj[n] = lx + ly;
    }
}

// ---------- kernel C: CE + final combine ----------
__global__ __launch_bounds__(256) void k_final(
    const float* __restrict__ logits, const int* __restrict__ tcls,
    const float* __restrict__ ew, const int* __restrict__ num_masks,
    const float* __restrict__ part_st, const float* __restrict__ part_t,
    const float* __restrict__ proj, float* __restrict__ out)
{
    __shared__ float red[4];
    const int t = threadIdx.x;
    float s1 = 0.f, s2 = 0.f;
    for (int i = t; i < NIMG * NROWG; i += 256) { s1 += part_st[i]; s2 += part_t[i]; }
    const float sum_st = blockReduceSum(s1, red);
    const float sum_t = blockReduceSum(s2, red);
    const float pj = (t < NIMG) ? proj[t] : 0.f;
    const float sum_pj = blockReduceSum(pj, red);

    float wn = 0.f, wsum = 0.f;
    if (t < 200) {
        const float* row = logits + t * 81;
        float mx = -3.4e38f;
        for (int c = 0; c < 81; c++) mx = fmaxf(mx, row[c]);
        float se = 0.f;
        for (int c = 0; c < 81; c++) se += expf(row[c] - mx);
        const float lse = mx + logf(se);
        const int tc = tcls[t];
        const float nll = lse - row[tc];
        const float wv = ew[tc];
        wn = wv * nll;
        wsum = wv;
    }
    const float Swn = blockReduceSum(wn, red);
    const float Sw = blockReduceSum(wsum, red);
    if (t == 0) {
        const float nm = (float)max(num_masks[0], 1);
        const float loss_ce = Swn / Sw;
        const float loss_pw = sum_st / fmaxf(sum_t, 1.f) / nm;
        const float loss_pj = sum_pj / nm;
        out[0] = loss_ce + loss_pw + loss_pj;
    }
}

extern "C" void kernel_launch(void* const* d_in, const int* in_sizes, int n_in,
                              void* d_out, int out_size, void* d_ws, size_t ws_size,
                              hipStream_t stream) {
    const float* pred_logits = (const float*)d_in[0];  // [2,100,81]
    const float* src         = (const float*)d_in[1];  // [64,256,256]
    const float* ew          = (const float*)d_in[2];  // [81]
    const float* ts          = (const float*)d_in[3];  // [64,8,256,256]
    const int*   tcls        = (const int*)d_in[4];    // [2,100]
    const int*   bm          = (const int*)d_in[5];    // [64,256,256]
    const int*   nmasks      = (const int*)d_in[6];    // [1]
    float* out = (float*)d_out;

    float* ws = (float*)d_ws;
    float* part_st   = ws;            // 2048
    float* part_t    = ws + 2048;     // 2048
    float* rowsig    = ws + 4096;     // 16384
    float* rowmax_b  = ws + 20480;    // 16384
    float* colpart_s = ws + 36864;    // 64*32*256 = 524288
    float* colpart_b = ws + 561152;   // 524288
    float* proj      = ws + 1085440;  // 64

    k_pairwise<<<dim3(NROWG, NIMG), 256, 0, stream>>>(src, ts, bm, part_st, part_t,
                                                      rowsig, rowmax_b, colpart_s, colpart_b);
    k_proj<<<NIMG, 256, 0, stream>>>(colpart_s, colpart_b, rowsig, rowmax_b, proj);
    k_final<<<1, 256, 0, stream>>>(pred_logits, tcls, ew, nmasks, part_st, part_t, proj, out);
}